// Round 4
// baseline (781.563 us; speedup 1.0000x reference)
//
#include <hip/hip_runtime.h>
#include <hip/hip_bf16.h>
#include <cstdint>

#define NN 40000
#define NE 100000
#define NEP 100032          // NE padded to multiple of 64
#define NB 1024

typedef _Float16 halfT;
typedef _Float16 half8 __attribute__((ext_vector_type(8)));
typedef float f32x4 __attribute__((ext_vector_type(4)));

static __device__ __forceinline__ float sigf(float x){ return 1.f/(1.f + expf(-x)); }

// ---------------- node embed: h = relu(x @ lin0_W^T + b) ----------------
__global__ __launch_bounds__(256) void k_lin0(const float* __restrict__ x,
    const float* __restrict__ W, const float* __restrict__ b, float* __restrict__ h){
    int gid = blockIdx.x * 256 + threadIdx.x;           // NN*32 threads
    int i = gid >> 5, c = gid & 31;
    const float* xr = x + (size_t)i * 30;
    const float* wr = W + (size_t)c * 30;
    float s = b[c];
    #pragma unroll
    for (int f = 0; f < 30; f++) s += xr[f] * wr[f];
    h[gid] = fmaxf(s, 0.f);
}

// ---------------- edge MLP layer 1: ehh = relu(edge_attr @ W1^T + b1) fp16, zero-pad rows
__global__ __launch_bounds__(256) void k_edge_mlp(const float* __restrict__ ea,
    const float* __restrict__ W1, const float* __restrict__ b1, halfT* __restrict__ eh){
    int gid = blockIdx.x * 256 + threadIdx.x;           // NEP*128 threads
    int e = gid >> 7, hh = gid & 127;
    if (e >= NE){ eh[gid] = (halfT)0.f; return; }
    const float* xr = ea + (size_t)e * 11;
    const float* wr = W1 + (size_t)hh * 11;
    float s = b1[hh];
    #pragma unroll
    for (int f = 0; f < 11; f++) s += xr[f] * wr[f];
    eh[gid] = (halfT)fmaxf(s, 0.f);
}

// ---------------- B-matrix prep: Bb2[p][k] = W2[j(p)][k] fp16, j(p)=(p&31)*32 + p/32
__global__ __launch_bounds__(256) void k_prepB(const float* __restrict__ W2, halfT* __restrict__ Bb2){
    int gid = blockIdx.x * 256 + threadIdx.x;           // 1024*128 threads
    int p = gid >> 7, k = gid & 127;
    int j = ((p & 31) << 5) | (p >> 5);
    Bb2[gid] = (halfT)W2[(size_t)j * 128 + k];
}

// ---------------- degree & graph counts ----------------
__global__ __launch_bounds__(256) void k_deg(const int* __restrict__ dst, float* __restrict__ deg, int E){
    int e = blockIdx.x * 256 + threadIdx.x;
    if (e < E) atomicAdd(&deg[dst[e]], 1.f);
}
__global__ __launch_bounds__(256) void k_counts(const int* __restrict__ batch, int* __restrict__ counts, int N){
    int i = blockIdx.x * 256 + threadIdx.x;
    if (i < N) atomicAdd(&counts[batch[i]], 1);
}
__global__ __launch_bounds__(1024) void k_scan(const int* __restrict__ counts, int* __restrict__ starts){
    __shared__ int s[1024];
    int t = threadIdx.x;
    s[t] = counts[t];
    __syncthreads();
    for (int off = 1; off < 1024; off <<= 1){
        int v = (t >= off) ? s[t - off] : 0;
        __syncthreads();
        s[t] += v;
        __syncthreads();
    }
    starts[t] = s[t] - counts[t];
    if (t == 1023) starts[1024] = s[1023];
}

// ---------------- fused NNConv message pass ----------------
// Per block: 64 edges. MFMA computes W_e tile window-by-window (4 windows x 256 p)
// into LDS (fp16), immediately contracted with u = h[src[e]]; msg accumulated in
// registers, one atomic scatter at the end.
// MFMA layouts identical to the round-3-validated k_we_mfma:
//   A: row = base+(l&15), k = (l>>4)*8 + i ; D: col = l&15, row = (l>>4)*4 + r.
__global__ __launch_bounds__(256) void k_msg_fused(const halfT* __restrict__ ehh,
    const halfT* __restrict__ Bb2, const float* __restrict__ b2,
    const float* __restrict__ h, const int* __restrict__ src, const int* __restrict__ dst,
    float* __restrict__ aggr){
    __shared__ halfT lout[64 * 264];
    __shared__ float s_u[64][33];
    __shared__ int s_src[64], s_dst[64];
    int tid = threadIdx.x;
    int w = tid >> 6, l = tid & 63;
    int ebl = blockIdx.x * 64;
    if (tid < 64){
        int e = ebl + tid;
        s_src[tid] = (e < NE) ? src[e] : 0;
        s_dst[tid] = (e < NE) ? dst[e] : 0;
    }
    __syncthreads();
    {   // gather u = h[src[e]] : 4 threads per edge, 8 floats each
        int e_loc = tid >> 2, part = tid & 3;
        const float* up = h + (size_t)s_src[e_loc] * 32 + part * 8;
        float4 v0 = *(const float4*)up;
        float4 v1 = *(const float4*)(up + 4);
        s_u[e_loc][part * 8 + 0] = v0.x; s_u[e_loc][part * 8 + 1] = v0.y;
        s_u[e_loc][part * 8 + 2] = v0.z; s_u[e_loc][part * 8 + 3] = v0.w;
        s_u[e_loc][part * 8 + 4] = v1.x; s_u[e_loc][part * 8 + 5] = v1.y;
        s_u[e_loc][part * 8 + 6] = v1.z; s_u[e_loc][part * 8 + 7] = v1.w;
    }
    // A fragments: 64 edges x 128 k, resident across all windows
    const halfT* A0 = ehh + (size_t)(ebl + (l & 15)) * 128 + (l >> 4) * 8;
    half8 afr[4][4];
    #pragma unroll
    for (int g = 0; g < 4; g++)
        #pragma unroll
        for (int ks = 0; ks < 4; ks++)
            afr[g][ks] = *(const half8*)(A0 + (size_t)g * 16 * 128 + ks * 32);
    float msg[8];
    #pragma unroll
    for (int i = 0; i < 8; i++) msg[i] = 0.f;
    int e_c = tid >> 2, grp = tid & 3;                  // contraction assignment
    #pragma unroll
    for (int win = 0; win < 4; win++){
        int p0 = win * 256;
        int pw = p0 + w * 64;
        const halfT* B0 = Bb2 + (size_t)(pw + (l & 15)) * 128 + (l >> 4) * 8;
        f32x4 acc[4][4];
        #pragma unroll
        for (int g = 0; g < 4; g++)
            #pragma unroll
            for (int pt = 0; pt < 4; pt++) acc[g][pt] = (f32x4){0.f, 0.f, 0.f, 0.f};
        #pragma unroll
        for (int ks = 0; ks < 4; ks++){
            half8 bb[4];
            #pragma unroll
            for (int pt = 0; pt < 4; pt++)
                bb[pt] = *(const half8*)(B0 + (size_t)pt * 16 * 128 + ks * 32);
            #pragma unroll
            for (int g = 0; g < 4; g++)
                #pragma unroll
                for (int pt = 0; pt < 4; pt++)
                    acc[g][pt] = __builtin_amdgcn_mfma_f32_16x16x32_f16(afr[g][ks], bb[pt], acc[g][pt], 0, 0, 0);
        }
        __syncthreads();                                // prev window's contraction done
        #pragma unroll
        for (int pt = 0; pt < 4; pt++){
            int p = pw + pt * 16 + (l & 15);
            float bias = b2[((p & 31) << 5) | (p >> 5)];
            int p_loc = w * 64 + pt * 16 + (l & 15);
            #pragma unroll
            for (int g = 0; g < 4; g++)
                #pragma unroll
                for (int r = 0; r < 4; r++){
                    int e_loc = g * 16 + (l >> 4) * 4 + r;
                    lout[e_loc * 264 + p_loc] = (halfT)(acc[g][pt][r] + bias);
                }
        }
        __syncthreads();                                // lout window ready
        // contraction: thread handles edge e_c, o_loc = grp*2 + {0,1}
        #pragma unroll
        for (int oo = 0; oo < 2; oo++){
            int o_loc = grp * 2 + oo;
            const half8* lp = (const half8*)(lout + e_c * 264 + o_loc * 32);
            float s = 0.f;
            #pragma unroll
            for (int q = 0; q < 4; q++){
                half8 v = lp[q];
                #pragma unroll
                for (int j = 0; j < 8; j++) s += s_u[e_c][q * 8 + j] * (float)v[j];
            }
            msg[win * 2 + oo] = s;
        }
    }
    int e = ebl + e_c;
    if (e < NE){
        int d = s_dst[e_c];
        #pragma unroll
        for (int win = 0; win < 4; win++)
            #pragma unroll
            for (int oo = 0; oo < 2; oo++){
                int o = win * 8 + grp * 2 + oo;
                atomicAdd(&aggr[(size_t)d * 32 + o], msg[win * 2 + oo]);
            }
    }
}

// ---------------- fused NNConv-epilogue + GRU: h = GRU(m, h) ----------------
__global__ __launch_bounds__(256) void k_gru(const float* __restrict__ aggr,
    const float* __restrict__ deg, float* __restrict__ h,
    const float* __restrict__ rootW, const float* __restrict__ cb,
    const float* __restrict__ Wih, const float* __restrict__ Whh,
    const float* __restrict__ bih, const float* __restrict__ bhh){
    __shared__ float s_root[1024];
    __shared__ float s_wih[3072];
    __shared__ float s_whh[3072];
    __shared__ float s_bih[96], s_bhh[96], s_cb[32];
    int tid = threadIdx.x;
    for (int idx = tid; idx < 1024; idx += 256) s_root[idx] = rootW[idx];
    for (int idx = tid; idx < 3072; idx += 256){ s_wih[idx] = Wih[idx]; s_whh[idx] = Whh[idx]; }
    if (tid < 96){ s_bih[tid] = bih[tid]; s_bhh[tid] = bhh[tid]; }
    if (tid < 32) s_cb[tid] = cb[tid];
    __syncthreads();
    int i = blockIdx.x * 256 + tid;
    if (i >= NN) return;
    float hq[32], mv[32], hn[32];
    const float* hr = h + (size_t)i * 32;
    #pragma unroll
    for (int k = 0; k < 8; k++) *(float4*)&hq[k * 4] = *(const float4*)(hr + k * 4);
    float invd = 1.f / fmaxf(deg[i], 1.f);
    const float* ar = aggr + (size_t)i * 32;
    #pragma unroll
    for (int c = 0; c < 32; c++){
        float s = ar[c] * invd + s_cb[c];
        #pragma unroll
        for (int k = 0; k < 32; k++) s += hq[k] * s_root[k * 32 + c];
        mv[c] = fmaxf(s, 0.f);
    }
    for (int j = 0; j < 32; j++){
        float gxr = s_bih[j], ghr = s_bhh[j];
        float gxz = s_bih[32 + j], ghz = s_bhh[32 + j];
        float gxn = s_bih[64 + j], ghn = s_bhh[64 + j];
        const float* wr0 = &s_wih[j * 32];
        const float* wr1 = &s_wih[(32 + j) * 32];
        const float* wr2 = &s_wih[(64 + j) * 32];
        const float* wh0 = &s_whh[j * 32];
        const float* wh1 = &s_whh[(32 + j) * 32];
        const float* wh2 = &s_whh[(64 + j) * 32];
        #pragma unroll
        for (int k = 0; k < 32; k++){
            float m = mv[k], hh = hq[k];
            gxr += m * wr0[k]; ghr += hh * wh0[k];
            gxz += m * wr1[k]; ghz += hh * wh1[k];
            gxn += m * wr2[k]; ghn += hh * wh2[k];
        }
        float r = sigf(gxr + ghr);
        float z = sigf(gxz + ghz);
        float n = tanhf(gxn + r * ghn);
        hn[j] = (1.f - z) * n + z * hq[j];
    }
    float* hw = h + (size_t)i * 32;
    #pragma unroll
    for (int k = 0; k < 8; k++) *(float4*)(hw + k * 4) = *(const float4*)&hn[k * 4];
}

// ---------------- Set2Set LSTM step (block per graph) ----------------
__global__ __launch_bounds__(128) void k_lstm(const float* __restrict__ q_star,
    float* __restrict__ hs, float* __restrict__ cs,
    const float* __restrict__ Wih, const float* __restrict__ Whh,
    const float* __restrict__ bih, const float* __restrict__ bhh){
    __shared__ float gbuf[128];
    int g = blockIdx.x, j = threadIdx.x;
    const float* q = q_star + (size_t)g * 64;
    const float* wr = Wih + (size_t)j * 64;
    float acc = bih[j] + bhh[j];
    #pragma unroll 8
    for (int k = 0; k < 64; k++) acc += q[k] * wr[k];
    const float* hr = hs + (size_t)g * 32;
    const float* wh = Whh + (size_t)j * 32;
    #pragma unroll 8
    for (int k = 0; k < 32; k++) acc += hr[k] * wh[k];
    gbuf[j] = acc;
    __syncthreads();
    if (j < 32){
        float iv = sigf(gbuf[j]);
        float fv = sigf(gbuf[32 + j]);
        float gv = tanhf(gbuf[64 + j]);
        float ov = sigf(gbuf[96 + j]);
        float cn = fv * cs[(size_t)g * 32 + j] + iv * gv;
        cs[(size_t)g * 32 + j] = cn;
        hs[(size_t)g * 32 + j] = ov * tanhf(cn);
    }
}

// ---------------- attention pooling (block=64 per graph) ----------------
__global__ __launch_bounds__(64) void k_attn(const float* __restrict__ h, const float* __restrict__ hs,
    const int* __restrict__ starts, float* __restrict__ e_buf, float* __restrict__ q_star){
    int g = blockIdx.x, l = threadIdx.x;
    int s0 = starts[g], s1 = starts[g + 1];
    int c = l & 31, grp = l >> 5;
    float hsv = hs[(size_t)g * 32 + c];
    float mx = -3.4e38f;
    for (int i = s0 + grp; i < s1; i += 2){
        float p = h[(size_t)i * 32 + c] * hsv;
        #pragma unroll
        for (int off = 1; off < 32; off <<= 1) p += __shfl_xor(p, off);
        if (c == 0) e_buf[i] = p;
        mx = fmaxf(mx, p);
    }
    mx = fmaxf(mx, __shfl_xor(mx, 32));
    float ssum = 0.f;
    for (int i = s0 + grp; i < s1; i += 2){
        if (c == 0) ssum += expf(e_buf[i] - mx);
    }
    #pragma unroll
    for (int off = 1; off < 64; off <<= 1) ssum += __shfl_xor(ssum, off);
    float inv = (ssum > 0.f) ? 1.f / ssum : 0.f;
    float acc = 0.f;
    for (int i = s0 + grp; i < s1; i += 2){
        float a = expf(e_buf[i] - mx) * inv;
        acc += a * h[(size_t)i * 32 + c];
    }
    acc += __shfl_xor(acc, 32);
    if (l < 32){
        q_star[(size_t)g * 64 + 32 + c] = acc;
        q_star[(size_t)g * 64 + c] = hsv;
    }
}

// ---------------- final: out = relu(q_star@lin1^T+b1) @ lin2^T + b2 ----------------
__global__ __launch_bounds__(64) void k_final(const float* __restrict__ q_star,
    const float* __restrict__ W1, const float* __restrict__ b1,
    const float* __restrict__ W2, const float* __restrict__ b2, float* __restrict__ out){
    int g = blockIdx.x, l = threadIdx.x;
    float p = 0.f;
    if (l < 32){
        const float* q = q_star + (size_t)g * 64;
        const float* wr = W1 + (size_t)l * 64;
        float s = b1[l];
        #pragma unroll 8
        for (int k = 0; k < 64; k++) s += q[k] * wr[k];
        p = fmaxf(s, 0.f) * W2[l];
    }
    #pragma unroll
    for (int off = 1; off < 64; off <<= 1) p += __shfl_xor(p, off);
    if (l == 0) out[g] = p + b2[0];
}

extern "C" void kernel_launch(void* const* d_in, const int* in_sizes, int n_in,
                              void* d_out, int out_size, void* d_ws, size_t ws_size,
                              hipStream_t stream){
    (void)in_sizes; (void)n_in; (void)out_size;
    const float* x        = (const float*)d_in[0];
    const float* ea       = (const float*)d_in[1];
    const int*   ei       = (const int*)d_in[2];
    const int*   batch    = (const int*)d_in[3];
    const float* lin0_W   = (const float*)d_in[4];
    const float* lin0_b   = (const float*)d_in[5];
    const float* mlp_W1   = (const float*)d_in[6];
    const float* mlp_b1   = (const float*)d_in[7];
    const float* mlp_W2   = (const float*)d_in[8];
    const float* mlp_b2   = (const float*)d_in[9];
    const float* root_W   = (const float*)d_in[10];
    const float* conv_b   = (const float*)d_in[11];
    const float* gWih     = (const float*)d_in[12];
    const float* gWhh     = (const float*)d_in[13];
    const float* gbih     = (const float*)d_in[14];
    const float* gbhh     = (const float*)d_in[15];
    const float* lWih     = (const float*)d_in[16];
    const float* lWhh     = (const float*)d_in[17];
    const float* lbih     = (const float*)d_in[18];
    const float* lbhh     = (const float*)d_in[19];
    const float* lin1_W   = (const float*)d_in[20];
    const float* lin1_b   = (const float*)d_in[21];
    const float* lin2_W   = (const float*)d_in[22];
    const float* lin2_b   = (const float*)d_in[23];
    const int* src = ei;
    const int* dst = ei + NE;
    float* out = (float*)d_out;

    char* w = (char*)d_ws;
    size_t off = 0;
    auto alloc = [&](size_t bytes) -> void* {
        void* p = w + off;
        off = (off + bytes + 255) & ~(size_t)255;
        return p;
    };
    float* h      = (float*)alloc((size_t)NN * 32 * 4);
    float* aggr   = (float*)alloc((size_t)NN * 32 * 4);
    float* deg    = (float*)alloc((size_t)NN * 4);
    float* e_buf  = (float*)alloc((size_t)NN * 4);
    int*   counts = (int*)alloc((size_t)NB * 4);
    int*   starts = (int*)alloc((size_t)(NB + 1) * 4);
    float* q_star = (float*)alloc((size_t)NB * 64 * 4);
    float* hs     = (float*)alloc((size_t)NB * 32 * 4);
    float* cs     = (float*)alloc((size_t)NB * 32 * 4);
    halfT* ehh    = (halfT*)alloc((size_t)NEP * 128 * 2);
    halfT* Bb2    = (halfT*)alloc((size_t)1024 * 128 * 2);
    if (ws_size < off) return;   // cannot run

    hipMemsetAsync(deg, 0, (size_t)NN * 4, stream);
    hipMemsetAsync(counts, 0, (size_t)NB * 4, stream);
    hipMemsetAsync(q_star, 0, (size_t)NB * 64 * 4, stream);
    hipMemsetAsync(hs, 0, (size_t)NB * 32 * 4, stream);
    hipMemsetAsync(cs, 0, (size_t)NB * 32 * 4, stream);

    k_lin0<<<(NN * 32) / 256, 256, 0, stream>>>(x, lin0_W, lin0_b, h);
    k_edge_mlp<<<(NEP * 128) / 256, 256, 0, stream>>>(ea, mlp_W1, mlp_b1, ehh);
    k_prepB<<<(1024 * 128) / 256, 256, 0, stream>>>(mlp_W2, Bb2);
    k_deg<<<(NE + 255) / 256, 256, 0, stream>>>(dst, deg, NE);
    k_counts<<<(NN + 255) / 256, 256, 0, stream>>>(batch, counts, NN);
    k_scan<<<1, 1024, 0, stream>>>(counts, starts);

    for (int t = 0; t < 3; t++){
        hipMemsetAsync(aggr, 0, (size_t)NN * 32 * 4, stream);
        k_msg_fused<<<NEP / 64, 256, 0, stream>>>(ehh, Bb2, mlp_b2, h, src, dst, aggr);
        k_gru<<<(NN + 255) / 256, 256, 0, stream>>>(aggr, deg, h, root_W, conv_b,
                                                    gWih, gWhh, gbih, gbhh);
    }

    for (int t = 0; t < 3; t++){
        k_lstm<<<NB, 128, 0, stream>>>(q_star, hs, cs, lWih, lWhh, lbih, lbhh);
        k_attn<<<NB, 64, 0, stream>>>(h, hs, starts, e_buf, q_star);
    }
    k_final<<<NB, 64, 0, stream>>>(q_star, lin1_W, lin1_b, lin2_W, lin2_b, out);
}